// Round 3
// baseline (5637.403 us; speedup 1.0000x reference)
//
#include <hip/hip_runtime.h>
#include <hip/hip_bf16.h>

typedef __bf16 bfx8 __attribute__((ext_vector_type(8)));
typedef float f32x4 __attribute__((ext_vector_type(4)));

// Problem dims: S=32 T=32 B=512 H=1024 E=256 A=1024 VS=64 VT=70 START=1
// ALL float tensors (inputs and output) are float32. MFMA runs on bf16 copies.

// ---- Device-global scratch (no ws_size dependency) ----
__device__ __attribute__((aligned(256))) float  g_h[512 * 1024];
__device__ __attribute__((aligned(256))) float  g_gi[512 * 3072];
__device__ __attribute__((aligned(256))) float  g_gh[512 * 3072];
__device__ __attribute__((aligned(256))) float  g_hpart[512 * 1024];
__device__ __attribute__((aligned(256))) __bf16 g_hb[512 * 1024];
__device__ __attribute__((aligned(256))) __bf16 g_Adec[512 * 1280];
__device__ __attribute__((aligned(256))) __bf16 g_enc_ops[(size_t)32 * 512 * 1024];
__device__ __attribute__((aligned(256))) __bf16 g_enc_part[(size_t)32 * 512 * 1024];
__device__ __attribute__((aligned(256))) __bf16 g_WattnT[(size_t)1024 * 2048];
__device__ __attribute__((aligned(256))) __bf16 g_Wihe[3072 * 256];
__device__ __attribute__((aligned(256))) __bf16 g_Whhe[3072 * 1024];
__device__ __attribute__((aligned(256))) __bf16 g_Wihd[3072 * 1280];
__device__ __attribute__((aligned(256))) __bf16 g_Whhd[3072 * 1024];
__device__ __attribute__((aligned(256))) __bf16 g_embs[64 * 256];
__device__ __attribute__((aligned(256))) __bf16 g_embt[70 * 256];
__device__ __attribute__((aligned(256))) int    g_x[512];

__device__ __forceinline__ float fast_tanh(float x) {
    float cx = fminf(fmaxf(x, -15.f), 15.f);
    float e = __expf(-2.f * cx);
    return (1.f - e) / (1.f + e);
}

// f32 -> bf16 copy, 4 elements/thread. n4 = n/4.
__global__ void k_cvt(const float* __restrict__ src, __bf16* __restrict__ dst,
                      int n4)
{
    int i = blockIdx.x * 256 + threadIdx.x;
    if (i >= n4) return;
    float4 v = ((const float4*)src)[i];
    __bf16 o[4] = {(__bf16)v.x, (__bf16)v.y, (__bf16)v.z, (__bf16)v.w};
    *(ushort2*)(dst + 4 * i) = *(ushort2*)o;  // 8B store
    *(ushort2*)(dst + 4 * i + 2) = *(ushort2*)(o + 2);
}

// ---------------------------------------------------------------------------
// C[M,N] = A[M,K] @ W[N,K]^T + bias, bf16 in, f32 acc. Tile 64x64, BK=32,
// 256 thr = 4 waves. Optional row-gather (arows clamped). cmode 0=f32, 1=bf16.
// ---------------------------------------------------------------------------
__global__ __launch_bounds__(256) void gemm_bt(
    const __bf16* __restrict__ Amat, int lda, const int* __restrict__ arows,
    int amax,
    const __bf16* __restrict__ Wmat, int ldw,
    const float* __restrict__ bias,
    void* __restrict__ Cout, int ldc, int cmode, int K)
{
    __shared__ __bf16 As[64][40];
    __shared__ __bf16 Ws[64][40];
    const int tid  = threadIdx.x;
    const int m0   = blockIdx.y * 64;
    const int n0   = blockIdx.x * 64;
    const int wave = tid >> 6;
    const int lane = tid & 63;
    const int srow = tid >> 2;
    const int scol = (tid & 3) << 3;

    long arow = m0 + srow;
    if (arows) {
        int v = arows[arow];
        arow = (v < 0) ? 0 : (v > amax ? amax : v);
    }
    const __bf16* aptr = Amat + arow * (long)lda + scol;
    const __bf16* wptr = Wmat + (long)(n0 + srow) * ldw + scol;

    f32x4 acc[4];
#pragma unroll
    for (int i = 0; i < 4; i++) acc[i] = (f32x4){0.f, 0.f, 0.f, 0.f};

    const int r15 = lane & 15;
    const int kk  = (lane >> 4) << 3;

    for (int k0 = 0; k0 < K; k0 += 32) {
        uint4 av = *(const uint4*)(aptr + k0);
        uint4 wv = *(const uint4*)(wptr + k0);
        __syncthreads();
        *(uint4*)(&As[srow][scol]) = av;
        *(uint4*)(&Ws[srow][scol]) = wv;
        __syncthreads();
        bfx8 a = *(const bfx8*)(&As[wave * 16 + r15][kk]);
#pragma unroll
        for (int n = 0; n < 4; n++) {
            bfx8 b = *(const bfx8*)(&Ws[n * 16 + r15][kk]);
            acc[n] = __builtin_amdgcn_mfma_f32_16x16x32_bf16(a, b, acc[n], 0, 0, 0);
        }
    }

    const int rowb = m0 + wave * 16 + (lane >> 4) * 4;
#pragma unroll
    for (int n = 0; n < 4; n++) {
        int c = n0 + n * 16 + r15;
        float bv = bias ? bias[c] : 0.f;
#pragma unroll
        for (int r = 0; r < 4; r++) {
            float v = acc[n][r] + bv;
            long off = (long)(rowb + r) * ldc + c;
            if (cmode == 0) ((float*)Cout)[off] = v;
            else            ((__bf16*)Cout)[off] = (__bf16)v;
        }
    }
}

// ---------------------------------------------------------------------------
__global__ void k_init(const int* __restrict__ target, float* __restrict__ out)
{
    int idx = blockIdx.x * 256 + threadIdx.x;
    if (idx < 512 * 1024) { g_h[idx] = 0.f; g_hb[idx] = (__bf16)0.f; }
    if (idx < 512) {
        int v = target[idx];
        g_x[idx] = (v < 0) ? 0 : (v > 69 ? 69 : v);
    }
    if (idx < 512 * 70) out[idx] = (idx % 70 == 1) ? 1.f : 0.f;
}

// W_attn f32 (2048,1024) -> g_WattnT bf16 (1024,2048)
__global__ __launch_bounds__(256) void k_transpose(const float* __restrict__ Wsrc)
{
    __shared__ float t[32][33];
    int bx = blockIdx.x;   // a-tile 0..31
    int by = blockIdx.y;   // f-tile 0..63
    int lx = threadIdx.x & 31, ly = threadIdx.x >> 5;
    for (int i = 0; i < 32; i += 8)
        t[ly + i][lx] = Wsrc[(long)(by * 32 + ly + i) * 1024 + bx * 32 + lx];
    __syncthreads();
    for (int i = 0; i < 32; i += 8)
        g_WattnT[(long)(bx * 32 + ly + i) * 2048 + by * 32 + lx] =
            (__bf16)t[lx][ly + i];
}

// GRU combine: h' = (1-z)n + z h.  enc_t >= 0: also store to enc_ops[enc_t].
__global__ void k_gru(int enc_t)
{
    int idx = blockIdx.x * 256 + threadIdx.x;
    int b = idx >> 10, j = idx & 1023;
    long o = (long)b * 3072 + j;
    float ir = g_gi[o], iz = g_gi[o + 1024], in_ = g_gi[o + 2048];
    float hr = g_gh[o], hz = g_gh[o + 1024], hn  = g_gh[o + 2048];
    float r = 1.f / (1.f + __expf(-(ir + hr)));
    float z = 1.f / (1.f + __expf(-(iz + hz)));
    float n = fast_tanh(in_ + r * hn);
    float hv = (1.f - z) * n + z * g_h[idx];
    g_h[idx] = hv;
    g_hb[idx] = (__bf16)hv;
    if (enc_t >= 0) g_enc_ops[(size_t)enc_t * 512 * 1024 + idx] = (__bf16)hv;
}

// Decoder input embedding -> Adec[:,1024:1280]
__global__ void k_embed_dec()
{
    int idx = blockIdx.x * 256 + threadIdx.x;  // < 512*256
    int b = idx >> 8, e = idx & 255;
    int xv = g_x[b];
    xv = (xv < 0) ? 0 : (xv > 69 ? 69 : xv);
    g_Adec[(long)b * 1280 + 1024 + e] = g_embt[xv * 256 + e];
}

// Attention for one decoder step. One block per b.
__global__ __launch_bounds__(256) void k_attn(
    const float* __restrict__ v_attn, float* __restrict__ attn_out)
{
    int b = blockIdx.x;
    int tid = threadIdx.x, lane = tid & 63, wave = tid >> 6;
    __shared__ float sc[32];
    __shared__ float sal[32];
    const float* hp = g_hpart + (long)b * 1024;
    for (int s = wave * 8; s < wave * 8 + 8; s++) {
        const __bf16* ep = g_enc_part + ((size_t)s * 512 + b) * 1024;
        float part = 0.f;
        for (int a = lane; a < 1024; a += 64)
            part += v_attn[a] * fast_tanh((float)ep[a] + hp[a]);
#pragma unroll
        for (int off = 32; off; off >>= 1) part += __shfl_down(part, off);
        if (lane == 0) sc[s] = part;
    }
    __syncthreads();
    float mx = sc[0];
    for (int s = 1; s < 32; s++) mx = fmaxf(mx, sc[s]);
    float den = 0.f;
    for (int s = 0; s < 32; s++) den += __expf(sc[s] - mx);
    float rden = 1.f / den;
    if (tid < 32) {
        float al = __expf(sc[tid] - mx) * rden;
        sal[tid] = al;
        attn_out[(long)b * 32 + tid] = al;
    }
    __syncthreads();
#pragma unroll
    for (int q = 0; q < 4; q++) {
        int hh = tid + q * 256;
        float c = 0.f;
#pragma unroll 4
        for (int s = 0; s < 32; s++)
            c += sal[s] * (float)g_enc_ops[((size_t)s * 512 + b) * 1024 + hh];
        g_Adec[(long)b * 1280 + hh] = (__bf16)c;
    }
}

// logits -> out row j+1 (f32); x update (tf ? target : argmax)
__global__ __launch_bounds__(256) void k_logits(
    const float* __restrict__ Wout, const float* __restrict__ bout,
    const int* __restrict__ target, const int* __restrict__ tf, int j,
    float* __restrict__ out)
{
    int b = blockIdx.x, tid = threadIdx.x;
    __shared__ float hs[1024];
    __shared__ float ls[70];
    for (int i = tid; i < 1024; i += 256) hs[i] = g_h[(long)b * 1024 + i];
    __syncthreads();
    if (tid < 70) {
        float s0 = 0, s1 = 0, s2 = 0, s3 = 0;
        for (int k = 0; k < 1024; k += 4) {
            s0 += hs[k]     * Wout[(long)k * 70 + tid];
            s1 += hs[k + 1] * Wout[(long)(k + 1) * 70 + tid];
            s2 += hs[k + 2] * Wout[(long)(k + 2) * 70 + tid];
            s3 += hs[k + 3] * Wout[(long)(k + 3) * 70 + tid];
        }
        float s = s0 + s1 + s2 + s3 + bout[tid];
        ls[tid] = s;
        out[(long)(j + 1) * 512 * 70 + (long)b * 70 + tid] = s;
    }
    __syncthreads();
    if (tid == 0) {
        float best = ls[0]; int bi = 0;
        for (int v = 1; v < 70; v++) if (ls[v] > best) { best = ls[v]; bi = v; }
        int nx = (*tf) ? target[(long)(j + 1) * 512 + b] : bi;
        g_x[b] = (nx < 0) ? 0 : (nx > 69 ? 69 : nx);
    }
}

// ---------------------------------------------------------------------------
extern "C" void kernel_launch(void* const* d_in, const int* in_sizes, int n_in,
                              void* d_out, int out_size, void* d_ws, size_t ws_size,
                              hipStream_t stream)
{
    const int*   source   = (const int*)d_in[0];
    const int*   target   = (const int*)d_in[1];
    const int*   tf       = (const int*)d_in[2];
    const float* emb_src  = (const float*)d_in[3];
    const float* W_ih_enc = (const float*)d_in[4];
    const float* W_hh_enc = (const float*)d_in[5];
    const float* b_ih_enc = (const float*)d_in[6];
    const float* b_hh_enc = (const float*)d_in[7];
    const float* emb_tgt  = (const float*)d_in[8];
    const float* W_attn   = (const float*)d_in[9];
    const float* b_attn   = (const float*)d_in[10];
    const float* v_attn   = (const float*)d_in[11];
    const float* W_ih_dec = (const float*)d_in[12];
    const float* W_hh_dec = (const float*)d_in[13];
    const float* b_ih_dec = (const float*)d_in[14];
    const float* b_hh_dec = (const float*)d_in[15];
    const float* W_out    = (const float*)d_in[16];
    const float* b_out    = (const float*)d_in[17];
    float* out = (float*)d_out;

    void *p_gi, *p_gh, *p_hpart, *p_hb, *p_Adec, *p_enc_ops, *p_enc_part,
         *p_WattnT, *p_Wihe, *p_Whhe, *p_Wihd, *p_Whhd, *p_embs, *p_embt;
    hipGetSymbolAddress(&p_gi,       HIP_SYMBOL(g_gi));
    hipGetSymbolAddress(&p_gh,       HIP_SYMBOL(g_gh));
    hipGetSymbolAddress(&p_hpart,    HIP_SYMBOL(g_hpart));
    hipGetSymbolAddress(&p_hb,       HIP_SYMBOL(g_hb));
    hipGetSymbolAddress(&p_Adec,     HIP_SYMBOL(g_Adec));
    hipGetSymbolAddress(&p_enc_ops,  HIP_SYMBOL(g_enc_ops));
    hipGetSymbolAddress(&p_enc_part, HIP_SYMBOL(g_enc_part));
    hipGetSymbolAddress(&p_WattnT,   HIP_SYMBOL(g_WattnT));
    hipGetSymbolAddress(&p_Wihe,     HIP_SYMBOL(g_Wihe));
    hipGetSymbolAddress(&p_Whhe,     HIP_SYMBOL(g_Whhe));
    hipGetSymbolAddress(&p_Wihd,     HIP_SYMBOL(g_Wihd));
    hipGetSymbolAddress(&p_Whhd,     HIP_SYMBOL(g_Whhd));
    hipGetSymbolAddress(&p_embs,     HIP_SYMBOL(g_embs));
    hipGetSymbolAddress(&p_embt,     HIP_SYMBOL(g_embt));
    __bf16* hb       = (__bf16*)p_hb;
    __bf16* Adec     = (__bf16*)p_Adec;
    __bf16* enc_ops  = (__bf16*)p_enc_ops;
    __bf16* enc_part = (__bf16*)p_enc_part;
    __bf16* WattnT   = (__bf16*)p_WattnT;

    // One-time f32 -> bf16 weight/embedding conversion
    auto cvt = [&](const float* s, void* d, int n) {
        k_cvt<<<(n / 4 + 255) / 256, 256, 0, stream>>>(s, (__bf16*)d, n / 4);
    };
    cvt(W_ih_enc, p_Wihe, 3072 * 256);
    cvt(W_hh_enc, p_Whhe, 3072 * 1024);
    cvt(W_ih_dec, p_Wihd, 3072 * 1280);
    cvt(W_hh_dec, p_Whhd, 3072 * 1024);
    cvt(emb_src,  p_embs, 64 * 256);
    cvt(emb_tgt,  p_embt, 70 * 256);

    k_init<<<2048, 256, 0, stream>>>(target, out);
    k_transpose<<<dim3(32, 64), 256, 0, stream>>>(W_attn);

    // -------- Encoder: 32 GRU steps --------
    for (int t = 0; t < 32; t++) {
        gemm_bt<<<dim3(48, 8), 256, 0, stream>>>(
            (__bf16*)p_embs, 256, source + t * 512, 63, (__bf16*)p_Wihe, 256,
            b_ih_enc, p_gi, 3072, 0, 256);
        gemm_bt<<<dim3(48, 8), 256, 0, stream>>>(
            hb, 1024, nullptr, 0, (__bf16*)p_Whhe, 1024, b_hh_enc,
            p_gh, 3072, 0, 1024);
        k_gru<<<2048, 256, 0, stream>>>(t);
    }

    // enc_part = enc_ops @ W_attn[H:2H]^T  (16384,1024,K=1024), bf16 out
    gemm_bt<<<dim3(16, 256), 256, 0, stream>>>(
        enc_ops, 1024, nullptr, 0, WattnT + 1024, 2048, nullptr,
        enc_part, 1024, 1, 1024);

    // -------- Decoder: 31 steps --------
    for (int j = 0; j < 31; j++) {
        gemm_bt<<<dim3(16, 8), 256, 0, stream>>>(
            hb, 1024, nullptr, 0, WattnT, 2048, b_attn,
            p_hpart, 1024, 0, 1024);
        k_embed_dec<<<512, 256, 0, stream>>>();
        k_attn<<<512, 256, 0, stream>>>(
            v_attn, out + 1146880 + (size_t)j * 512 * 32);
        gemm_bt<<<dim3(48, 8), 256, 0, stream>>>(
            Adec, 1280, nullptr, 0, (__bf16*)p_Wihd, 1280, b_ih_dec,
            p_gi, 3072, 0, 1280);
        gemm_bt<<<dim3(48, 8), 256, 0, stream>>>(
            hb, 1024, nullptr, 0, (__bf16*)p_Whhd, 1024, b_hh_dec,
            p_gh, 3072, 0, 1024);
        k_gru<<<2048, 256, 0, stream>>>(-1);
        k_logits<<<512, 256, 0, stream>>>(W_out, b_out, target, tf, j, out);
    }
}

// Round 4
// 3683.087 us; speedup vs baseline: 1.5306x; 1.5306x over previous
//
#include <hip/hip_runtime.h>
#include <hip/hip_bf16.h>

typedef __bf16 bfx8 __attribute__((ext_vector_type(8)));
typedef __bf16 bfx4 __attribute__((ext_vector_type(4)));
typedef float f32x4 __attribute__((ext_vector_type(4)));

// Dims: S=32 T=32 B=512 H=1024 E=256 A=1024 VS=64 VT=70 START=1
// Floats are f32 in/out; MFMA on bf16 copies; h kept f32 master.

__device__ __attribute__((aligned(256))) float  g_h[512 * 1024];
__device__ __attribute__((aligned(256))) float  g_hpart[512 * 1024];
__device__ __attribute__((aligned(256))) __bf16 g_hb[2][512 * 1024];  // ping-pong
__device__ __attribute__((aligned(256))) __bf16 g_Adec[512 * 1280];
__device__ __attribute__((aligned(256))) __bf16 g_enc_ops[(size_t)32 * 512 * 1024];
__device__ __attribute__((aligned(256))) __bf16 g_enc_part[(size_t)32 * 512 * 1024];
__device__ __attribute__((aligned(256))) __bf16 g_WattnT[(size_t)1024 * 2048];
__device__ __attribute__((aligned(256))) __bf16 g_Whhe[3072 * 1024];
__device__ __attribute__((aligned(256))) __bf16 g_Wihe[3072 * 256];
__device__ __attribute__((aligned(256))) __bf16 g_Whhd[3072 * 1024];
__device__ __attribute__((aligned(256))) __bf16 g_Wihd[3072 * 1280];
__device__ __attribute__((aligned(256))) __bf16 g_WoutT[128 * 1024];
__device__ __attribute__((aligned(256))) __bf16 g_embs[64 * 256];
__device__ __attribute__((aligned(256))) __bf16 g_embt[70 * 256];

__device__ __forceinline__ float fast_tanh(float x) {
    float cx = fminf(fmaxf(x, -15.f), 15.f);
    float e = __expf(-2.f * cx);
    return (1.f - e) / (1.f + e);
}

// f32 -> bf16 copy, 4 elems/thread
__global__ void k_cvt(const float* __restrict__ src, __bf16* __restrict__ dst,
                      int n4)
{
    int i = blockIdx.x * 256 + threadIdx.x;
    if (i >= n4) return;
    float4 v = ((const float4*)src)[i];
    __bf16 o[4] = {(__bf16)v.x, (__bf16)v.y, (__bf16)v.z, (__bf16)v.w};
    *(ushort2*)(dst + 4 * i) = *(ushort2*)o;
    *(ushort2*)(dst + 4 * i + 2) = *(ushort2*)(o + 2);
}

// ---------------------------------------------------------------------------
// Generic C[M,N] = A[M,K] @ W[N,K]^T + bias (f32), bf16 in, f32 acc.
// 64x64 tile, BK=32. cmode 0=f32 out, 1=bf16 out. Write only cols < nguard.
// ---------------------------------------------------------------------------
__global__ __launch_bounds__(256) void gemm_bt(
    const __bf16* __restrict__ Amat, int lda,
    const __bf16* __restrict__ Wmat, int ldw,
    const float* __restrict__ bias,
    void* __restrict__ Cout, int ldc, int cmode, int K, int nguard)
{
    __shared__ __bf16 As[64][40];
    __shared__ __bf16 Ws[64][40];
    const int tid  = threadIdx.x;
    const int m0   = blockIdx.y * 64;
    const int n0   = blockIdx.x * 64;
    const int wave = tid >> 6;
    const int lane = tid & 63;
    const int srow = tid >> 2;
    const int scol = (tid & 3) << 3;

    const __bf16* aptr = Amat + (size_t)(m0 + srow) * lda + scol;
    const __bf16* wptr = Wmat + (size_t)(n0 + srow) * ldw + scol;

    f32x4 acc[4];
#pragma unroll
    for (int i = 0; i < 4; i++) acc[i] = (f32x4){0.f, 0.f, 0.f, 0.f};

    const int r15 = lane & 15;
    const int kk  = (lane >> 4) << 3;

    for (int k0 = 0; k0 < K; k0 += 32) {
        uint4 av = *(const uint4*)(aptr + k0);
        uint4 wv = *(const uint4*)(wptr + k0);
        __syncthreads();
        *(uint4*)(&As[srow][scol]) = av;
        *(uint4*)(&Ws[srow][scol]) = wv;
        __syncthreads();
        bfx8 a = *(const bfx8*)(&As[wave * 16 + r15][kk]);
#pragma unroll
        for (int n = 0; n < 4; n++) {
            bfx8 b = *(const bfx8*)(&Ws[n * 16 + r15][kk]);
            acc[n] = __builtin_amdgcn_mfma_f32_16x16x32_bf16(a, b, acc[n], 0, 0, 0);
        }
    }

    const int rowb = m0 + wave * 16 + (lane >> 4) * 4;
#pragma unroll
    for (int n = 0; n < 4; n++) {
        int c = n0 + n * 16 + r15;
        if (c >= nguard) continue;
        float bv = bias ? bias[c] : 0.f;
#pragma unroll
        for (int r = 0; r < 4; r++) {
            float v = acc[n][r] + bv;
            size_t off = (size_t)(rowb + r) * ldc + c;
            if (cmode == 0) ((float*)Cout)[off] = v;
            else            ((__bf16*)Cout)[off] = (__bf16)v;
        }
    }
}

// ---------------------------------------------------------------------------
// Fused recurrent step: two GEMMs (gh = hb_in @ W1^T; gi = A2 @ W2^T) + GRU.
// Block: 32 batch rows x 64 j-cols x 3 gate slabs. grid (16,16) = 256 blocks.
// Writes g_h (f32 master), hb_out (bf16), optionally enc_ops[enc_t].
// ---------------------------------------------------------------------------
__global__ __launch_bounds__(256) void gru_step(
    const __bf16* __restrict__ hb_in, __bf16* __restrict__ hb_out,
    const __bf16* __restrict__ W1, const float* __restrict__ b1,
    const __bf16* __restrict__ A2, int lda2,
    const int* __restrict__ arows2, int amax2,
    const __bf16* __restrict__ W2, int ldw2, const float* __restrict__ b2,
    int K2, int enc_t)
{
    __shared__ __bf16 As[32][40];
    __shared__ __bf16 Ws[3][64][40];
    const int tid  = threadIdx.x;
    const int j0   = blockIdx.x * 64;
    const int m0   = blockIdx.y * 32;
    const int wave = tid >> 6, lane = tid & 63;
    const int r15  = lane & 15, q = lane >> 4;
    const int kk   = q << 3;

    const int war = tid >> 2, wac = (tid & 3) << 3;  // W stage: 64 rows x 8 cols
    const int aar = tid >> 3, aac = (tid & 7) << 2;  // A stage: 32 rows x 4 cols

    f32x4 acc1[3][2], acc2[3][2];
#pragma unroll
    for (int s = 0; s < 3; s++)
#pragma unroll
        for (int rt = 0; rt < 2; rt++) {
            acc1[s][rt] = (f32x4){0.f, 0.f, 0.f, 0.f};
            acc2[s][rt] = (f32x4){0.f, 0.f, 0.f, 0.f};
        }

    // ---- phase 1: gh = hb_in @ W1^T (K=1024) ----
    {
        const __bf16* a1p = hb_in + (size_t)(m0 + aar) * 1024 + aac;
        const __bf16* w1p0 = W1 + (size_t)(j0 + war) * 1024 + wac;
        const __bf16* w1p1 = W1 + (size_t)(1024 + j0 + war) * 1024 + wac;
        const __bf16* w1p2 = W1 + (size_t)(2048 + j0 + war) * 1024 + wac;
        for (int k0 = 0; k0 < 1024; k0 += 32) {
            uint2 av  = *(const uint2*)(a1p + k0);
            uint4 wv0 = *(const uint4*)(w1p0 + k0);
            uint4 wv1 = *(const uint4*)(w1p1 + k0);
            uint4 wv2 = *(const uint4*)(w1p2 + k0);
            __syncthreads();
            *(uint2*)(&As[aar][aac]) = av;
            *(uint4*)(&Ws[0][war][wac]) = wv0;
            *(uint4*)(&Ws[1][war][wac]) = wv1;
            *(uint4*)(&Ws[2][war][wac]) = wv2;
            __syncthreads();
            bfx8 a0 = *(const bfx8*)(&As[r15][kk]);
            bfx8 a1 = *(const bfx8*)(&As[16 + r15][kk]);
#pragma unroll
            for (int s = 0; s < 3; s++) {
                bfx8 b = *(const bfx8*)(&Ws[s][wave * 16 + r15][kk]);
                acc1[s][0] = __builtin_amdgcn_mfma_f32_16x16x32_bf16(a0, b, acc1[s][0], 0, 0, 0);
                acc1[s][1] = __builtin_amdgcn_mfma_f32_16x16x32_bf16(a1, b, acc1[s][1], 0, 0, 0);
            }
        }
    }
    // ---- phase 2: gi = A2 @ W2^T (K=K2), optional row gather ----
    {
        long arow = m0 + aar;
        if (arows2) {
            int v = arows2[arow];
            arow = (v < 0) ? 0 : (v > amax2 ? amax2 : v);
        }
        const __bf16* a2p = A2 + arow * (long)lda2 + aac;
        const __bf16* w2p0 = W2 + (size_t)(j0 + war) * ldw2 + wac;
        const __bf16* w2p1 = W2 + (size_t)(1024 + j0 + war) * ldw2 + wac;
        const __bf16* w2p2 = W2 + (size_t)(2048 + j0 + war) * ldw2 + wac;
        for (int k0 = 0; k0 < K2; k0 += 32) {
            uint2 av  = *(const uint2*)(a2p + k0);
            uint4 wv0 = *(const uint4*)(w2p0 + k0);
            uint4 wv1 = *(const uint4*)(w2p1 + k0);
            uint4 wv2 = *(const uint4*)(w2p2 + k0);
            __syncthreads();
            *(uint2*)(&As[aar][aac]) = av;
            *(uint4*)(&Ws[0][war][wac]) = wv0;
            *(uint4*)(&Ws[1][war][wac]) = wv1;
            *(uint4*)(&Ws[2][war][wac]) = wv2;
            __syncthreads();
            bfx8 a0 = *(const bfx8*)(&As[r15][kk]);
            bfx8 a1 = *(const bfx8*)(&As[16 + r15][kk]);
#pragma unroll
            for (int s = 0; s < 3; s++) {
                bfx8 b = *(const bfx8*)(&Ws[s][wave * 16 + r15][kk]);
                acc2[s][0] = __builtin_amdgcn_mfma_f32_16x16x32_bf16(a0, b, acc2[s][0], 0, 0, 0);
                acc2[s][1] = __builtin_amdgcn_mfma_f32_16x16x32_bf16(a1, b, acc2[s][1], 0, 0, 0);
            }
        }
    }
    // ---- GRU epilogue ----
    const int j = j0 + wave * 16 + r15;
    float bb10 = b1[j], bb11 = b1[1024 + j], bb12 = b1[2048 + j];
    float bb20 = b2[j], bb21 = b2[1024 + j], bb22 = b2[2048 + j];
#pragma unroll
    for (int rt = 0; rt < 2; rt++) {
#pragma unroll
        for (int reg = 0; reg < 4; reg++) {
            int b_ = m0 + rt * 16 + q * 4 + reg;
            float gh0 = acc1[0][rt][reg] + bb10;
            float gh1 = acc1[1][rt][reg] + bb11;
            float gh2 = acc1[2][rt][reg] + bb12;
            float gi0 = acc2[0][rt][reg] + bb20;
            float gi1 = acc2[1][rt][reg] + bb21;
            float gi2 = acc2[2][rt][reg] + bb22;
            float r = 1.f / (1.f + __expf(-(gi0 + gh0)));
            float z = 1.f / (1.f + __expf(-(gi1 + gh1)));
            float n = fast_tanh(gi2 + r * gh2);
            size_t off = (size_t)b_ * 1024 + j;
            float hv = (1.f - z) * n + z * g_h[off];
            g_h[off] = hv;
            hb_out[off] = (__bf16)hv;
            if (enc_t >= 0)
                g_enc_ops[(size_t)enc_t * 524288 + off] = (__bf16)hv;
        }
    }
}

// ---------------------------------------------------------------------------
__global__ void k_init(float* __restrict__ out)
{
    int idx = blockIdx.x * 256 + threadIdx.x;
    if (idx < 512 * 1024) { g_h[idx] = 0.f; g_hb[0][idx] = (__bf16)0.f; }
    if (idx < 512 * 70) out[idx] = (idx % 70 == 1) ? 1.f : 0.f;
}

// W_attn f32 (2048,1024) -> g_WattnT bf16 (1024,2048)
__global__ __launch_bounds__(256) void k_transpose(const float* __restrict__ Wsrc)
{
    __shared__ float t[32][33];
    int bx = blockIdx.x, by = blockIdx.y;
    int lx = threadIdx.x & 31, ly = threadIdx.x >> 5;
    for (int i = 0; i < 32; i += 8)
        t[ly + i][lx] = Wsrc[(size_t)(by * 32 + ly + i) * 1024 + bx * 32 + lx];
    __syncthreads();
    for (int i = 0; i < 32; i += 8)
        g_WattnT[(size_t)(bx * 32 + ly + i) * 2048 + by * 32 + lx] =
            (__bf16)t[lx][ly + i];
}

// W_out f32 (1024,70) -> g_WoutT bf16 (128,1024), rows >=70 zero
__global__ void k_cvtWout(const float* __restrict__ W)
{
    int idx = blockIdx.x * 256 + threadIdx.x;  // < 128*1024
    int c = idx >> 10, k = idx & 1023;
    g_WoutT[idx] = (__bf16)((c < 70) ? W[k * 70 + c] : 0.f);
}

// ---------------------------------------------------------------------------
// Attention step: x-select (target/argmax of prev logits) + embed + scores +
// softmax + alpha out + ctx. One block per batch b.
// ---------------------------------------------------------------------------
__global__ __launch_bounds__(256) void k_attn(
    int j, const int* __restrict__ target, const int* __restrict__ tf,
    const float* __restrict__ v_attn, float* __restrict__ out)
{
    const int b = blockIdx.x, tid = threadIdx.x;
    const int lane = tid & 63, wave = tid >> 6;
    __shared__ float sc[32], sal[32];
    __shared__ int sx;
    if (wave == 0) {
        int xv;
        if (j == 0) xv = target[b];
        else if (*tf) xv = target[j * 512 + b];
        else {
            const float* row = out + (size_t)j * 35840 + b * 70;
            float bv = row[lane]; int bi = lane;
            if (lane < 6) {
                float v2 = row[lane + 64];
                if (v2 > bv) { bv = v2; bi = lane + 64; }
            }
#pragma unroll
            for (int off = 32; off; off >>= 1) {
                float ov = __shfl_down(bv, off);
                int   oi = __shfl_down(bi, off);
                if (ov > bv || (ov == bv && oi < bi)) { bv = ov; bi = oi; }
            }
            xv = bi;
        }
        if (lane == 0) sx = (xv < 0) ? 0 : (xv > 69 ? 69 : xv);
    }
    // per-lane h_part & v fragments (fixed a-set across s)
    float hpv[16], vsv[16];
    {
        const float* hp = g_hpart + (size_t)b * 1024;
#pragma unroll
        for (int u = 0; u < 8; u++) {
            hpv[u]     = hp[lane * 8 + u];
            hpv[8 + u] = hp[512 + lane * 8 + u];
            vsv[u]     = v_attn[lane * 8 + u];
            vsv[8 + u] = v_attn[512 + lane * 8 + u];
        }
    }
    __syncthreads();
    g_Adec[(size_t)b * 1280 + 1024 + tid] = g_embt[sx * 256 + tid];
    for (int s = wave * 8; s < wave * 8 + 8; s++) {
        const __bf16* ep = g_enc_part + ((size_t)s * 512 + b) * 1024;
        bfx8 e0 = *(const bfx8*)(ep + lane * 8);
        bfx8 e1 = *(const bfx8*)(ep + 512 + lane * 8);
        float part = 0.f;
#pragma unroll
        for (int u = 0; u < 8; u++) {
            part += vsv[u]     * fast_tanh((float)e0[u] + hpv[u]);
            part += vsv[8 + u] * fast_tanh((float)e1[u] + hpv[8 + u]);
        }
#pragma unroll
        for (int off = 32; off; off >>= 1) part += __shfl_down(part, off);
        if (lane == 0) sc[s] = part;
    }
    __syncthreads();
    float mx = sc[0];
#pragma unroll
    for (int s = 1; s < 32; s++) mx = fmaxf(mx, sc[s]);
    float den = 0.f;
#pragma unroll
    for (int s = 0; s < 32; s++) den += __expf(sc[s] - mx);
    float rden = 1.f / den;
    if (tid < 32) {
        float al = __expf(sc[tid] - mx) * rden;
        sal[tid] = al;
        out[1146880 + (size_t)j * 16384 + b * 32 + tid] = al;
    }
    __syncthreads();
    float c0 = 0, c1 = 0, c2 = 0, c3 = 0;
    const __bf16* eo = g_enc_ops + (size_t)b * 1024 + tid * 4;
#pragma unroll 4
    for (int s = 0; s < 32; s++) {
        bfx4 e = *(const bfx4*)(eo + (size_t)s * 524288);
        float al = sal[s];
        c0 += al * (float)e[0]; c1 += al * (float)e[1];
        c2 += al * (float)e[2]; c3 += al * (float)e[3];
    }
    bfx4 o = {(__bf16)c0, (__bf16)c1, (__bf16)c2, (__bf16)c3};
    *(bfx4*)(&g_Adec[(size_t)b * 1280 + tid * 4]) = o;
}

// ---------------------------------------------------------------------------
extern "C" void kernel_launch(void* const* d_in, const int* in_sizes, int n_in,
                              void* d_out, int out_size, void* d_ws, size_t ws_size,
                              hipStream_t stream)
{
    const int*   source   = (const int*)d_in[0];
    const int*   target   = (const int*)d_in[1];
    const int*   tf       = (const int*)d_in[2];
    const float* emb_src  = (const float*)d_in[3];
    const float* W_ih_enc = (const float*)d_in[4];
    const float* W_hh_enc = (const float*)d_in[5];
    const float* b_ih_enc = (const float*)d_in[6];
    const float* b_hh_enc = (const float*)d_in[7];
    const float* emb_tgt  = (const float*)d_in[8];
    const float* W_attn   = (const float*)d_in[9];
    const float* b_attn   = (const float*)d_in[10];
    const float* v_attn   = (const float*)d_in[11];
    const float* W_ih_dec = (const float*)d_in[12];
    const float* W_hh_dec = (const float*)d_in[13];
    const float* b_ih_dec = (const float*)d_in[14];
    const float* b_hh_dec = (const float*)d_in[15];
    const float* W_out    = (const float*)d_in[16];
    const float* b_out    = (const float*)d_in[17];
    float* out = (float*)d_out;

    void *p_hb, *p_hpart, *p_Adec, *p_enc_ops, *p_enc_part, *p_WattnT,
         *p_Whhe, *p_Wihe, *p_Whhd, *p_Wihd, *p_WoutT, *p_embs, *p_embt;
    hipGetSymbolAddress(&p_hb,       HIP_SYMBOL(g_hb));
    hipGetSymbolAddress(&p_hpart,    HIP_SYMBOL(g_hpart));
    hipGetSymbolAddress(&p_Adec,     HIP_SYMBOL(g_Adec));
    hipGetSymbolAddress(&p_enc_ops,  HIP_SYMBOL(g_enc_ops));
    hipGetSymbolAddress(&p_enc_part, HIP_SYMBOL(g_enc_part));
    hipGetSymbolAddress(&p_WattnT,   HIP_SYMBOL(g_WattnT));
    hipGetSymbolAddress(&p_Whhe,     HIP_SYMBOL(g_Whhe));
    hipGetSymbolAddress(&p_Wihe,     HIP_SYMBOL(g_Wihe));
    hipGetSymbolAddress(&p_Whhd,     HIP_SYMBOL(g_Whhd));
    hipGetSymbolAddress(&p_Wihd,     HIP_SYMBOL(g_Wihd));
    hipGetSymbolAddress(&p_WoutT,    HIP_SYMBOL(g_WoutT));
    hipGetSymbolAddress(&p_embs,     HIP_SYMBOL(g_embs));
    hipGetSymbolAddress(&p_embt,     HIP_SYMBOL(g_embt));
    __bf16* hb0      = (__bf16*)p_hb;
    __bf16* hb1      = hb0 + 512 * 1024;
    __bf16* Adec     = (__bf16*)p_Adec;
    __bf16* enc_ops  = (__bf16*)p_enc_ops;
    __bf16* enc_part = (__bf16*)p_enc_part;
    __bf16* WattnT   = (__bf16*)p_WattnT;
    __bf16* WoutT    = (__bf16*)p_WoutT;

    auto cvt = [&](const float* s, void* d, int n) {
        k_cvt<<<(n / 4 + 255) / 256, 256, 0, stream>>>(s, (__bf16*)d, n / 4);
    };
    cvt(W_hh_enc, p_Whhe, 3072 * 1024);
    cvt(W_ih_enc, p_Wihe, 3072 * 256);
    cvt(W_hh_dec, p_Whhd, 3072 * 1024);
    cvt(W_ih_dec, p_Wihd, 3072 * 1280);
    cvt(emb_src,  p_embs, 64 * 256);
    cvt(emb_tgt,  p_embt, 70 * 256);
    k_transpose<<<dim3(32, 64), 256, 0, stream>>>(W_attn);
    k_cvtWout<<<512, 256, 0, stream>>>(W_out);
    k_init<<<2048, 256, 0, stream>>>(out);

    // -------- Encoder: 32 fused steps --------
    for (int t = 0; t < 32; t++) {
        __bf16* hin  = (t & 1) ? hb1 : hb0;
        __bf16* hout = (t & 1) ? hb0 : hb1;
        gru_step<<<dim3(16, 16), 256, 0, stream>>>(
            hin, hout, (__bf16*)p_Whhe, b_hh_enc,
            (__bf16*)p_embs, 256, source + t * 512, 63,
            (__bf16*)p_Wihe, 256, b_ih_enc, 256, t);
    }
    // h_enc lands in hb0 (t=31 writes hb0)

    // enc_part = enc_ops @ W_attn[H:2H]^T  (16384,1024,K=1024), bf16 out
    gemm_bt<<<dim3(16, 256), 256, 0, stream>>>(
        enc_ops, 1024, WattnT + 1024, 2048, nullptr,
        enc_part, 1024, 1, 1024, 1 << 30);

    // -------- Decoder: 31 steps --------
    for (int j = 0; j < 31; j++) {
        __bf16* hin  = (j & 1) ? hb1 : hb0;
        __bf16* hout = (j & 1) ? hb0 : hb1;
        // h_part = h @ W_attn[0:H]^T + b_attn
        gemm_bt<<<dim3(16, 8), 256, 0, stream>>>(
            hin, 1024, WattnT, 2048, b_attn, p_hpart, 1024, 0, 1024, 1 << 30);
        k_attn<<<512, 256, 0, stream>>>(j, target, tf, v_attn, out);
        gru_step<<<dim3(16, 16), 256, 0, stream>>>(
            hin, hout, (__bf16*)p_Whhd, b_hh_dec,
            Adec, 1280, nullptr, 0,
            (__bf16*)p_Wihd, 1280, b_ih_dec, 1280, -1);
        // logits = h_new @ W_out + b_out -> out row j+1
        gemm_bt<<<dim3(2, 8), 256, 0, stream>>>(
            hout, 1024, WoutT, 1024, b_out,
            out + (size_t)(j + 1) * 35840, 70, 0, 1024, 70);
    }
}